// Round 4
// baseline (605.145 us; speedup 1.0000x reference)
//
#include <hip/hip_runtime.h>
#include <cstdint>
#include <cstddef>

// ---------------------------------------------------------------------------
// DynaResidualBlock: hypernet GEMM (MFMA, hi/lo bf16 split = fp32-accurate)
//  -> per-sample 1x1 conv chain (bf16 MFMA)
//   FIN=64 FOUT=64 FH=128 LAT=512  B=16  H*W=16384
//   sizes = [8192,16384,16384,8192,4096,128,128,128,64,64], KTOT=53760
// ---------------------------------------------------------------------------

typedef short bf16x8 __attribute__((ext_vector_type(8)));   // 8 bf16 = 4 VGPRs
typedef float f32x4  __attribute__((ext_vector_type(4)));
typedef float f32x16 __attribute__((ext_vector_type(16)));  // MFMA 32x32 acc

#define DEVFN static __device__ __forceinline__

// frag = 32m x 16k = 512 bf16 = 1 KB (lane l holds 16 B at l*16)
// w_ws frag order: in[0..16) mida[16..48) midb[48..80) out[80..96) short[96..104)
constexpr int WELEM      = 53248;           // bf16 weight elements per sample
constexpr size_t WS_WSHORTS = (size_t)WELEM;
constexpr size_t WS_WBYTES_TOT = (size_t)16 * WELEM * 2;     // 1,703,936
constexpr size_t WS_BOFF  = WS_WBYTES_TOT;                   // b_ws: 16*512 f32
constexpr size_t WS_AHOFF = WS_BOFF + 16 * 512 * 4;          // ah frags: 16 KB
constexpr size_t WS_ALOFF = WS_AHOFF + 16384;                // al frags: 16 KB

DEVFN unsigned bf16rne(float f) {
  unsigned u = __builtin_bit_cast(unsigned, f);
  return (u + 0x7fffu + ((u >> 16) & 1u)) >> 16;
}

#if defined(__has_builtin)
#if __has_builtin(__builtin_amdgcn_cvt_pk_bf16_f32)
#define HAVE_CVT_PK_BF16 1
#endif
#endif

DEVFN unsigned pk2(float lo, float hi) {
#ifdef HAVE_CVT_PK_BF16
  typedef __bf16 bf16x2_t __attribute__((ext_vector_type(2)));
  bf16x2_t r = __builtin_amdgcn_cvt_pk_bf16_f32(lo, hi);
  return __builtin_bit_cast(unsigned, r);
#else
  return bf16rne(lo) | (bf16rne(hi) << 16);
#endif
}

// ---------------------------------------------------------------------------
// Kernel 0: lat -> hi/lo bf16 A-frags for mfma_16x16x32.
// ---------------------------------------------------------------------------
__global__ __launch_bounds__(256) void lat_prep(
    const float* __restrict__ lat, unsigned short* __restrict__ ah_ws,
    unsigned short* __restrict__ al_ws) {
  const int id = blockIdx.x * 256 + threadIdx.x;  // 0..1023
  const int s = id >> 6, l = id & 63;
  const int m = l & 15, q = l >> 4;
  const float* ap = lat + m * 512 + s * 32 + q * 8;
  float f[8];
#pragma unroll
  for (int j = 0; j < 8; ++j) f[j] = ap[j];
  unsigned H[4], L[4];
#pragma unroll
  for (int p = 0; p < 4; ++p) {
    const unsigned u0 = __builtin_bit_cast(unsigned, f[2 * p]);
    const unsigned u1 = __builtin_bit_cast(unsigned, f[2 * p + 1]);
    const unsigned h0 = u0 & 0xFFFF0000u, h1 = u1 & 0xFFFF0000u;
    H[p] = (h0 >> 16) | h1;
    const float lo0 = f[2 * p] - __builtin_bit_cast(float, h0);
    const float lo1 = f[2 * p + 1] - __builtin_bit_cast(float, h1);
    L[p] = pk2(lo0, lo1);
  }
  *(uint4*)&ah_ws[(size_t)(s * 64 + l) * 8] = make_uint4(H[0], H[1], H[2], H[3]);
  *(uint4*)&al_ws[(size_t)(s * 64 + l) * 8] = make_uint4(L[0], L[1], L[2], L[3]);
}

// ---------------------------------------------------------------------------
// Kernel 1: ks = lat @ W.T + bias via MFMA 16x16x32 (hi/lo split, 3 mfma/step)
// 420 blocks x 4 waves x 2 tiles = 3360 tiles of 16 columns; all waves
// resident in one dispatch round (1680 <= 2048). 16 KB/wave B-stream in
// flight -> 128 KB/CU, HBM-latency covered.
// ---------------------------------------------------------------------------
#define MFMA16(A, B, C) __builtin_amdgcn_mfma_f32_16x16x32_bf16((A), (B), (C), 0, 0, 0)

__global__ __launch_bounds__(256, 2) void hyper_gemm(
    const float* __restrict__ W, const float* __restrict__ bias,
    const unsigned short* __restrict__ ah_ws,
    const unsigned short* __restrict__ al_ws,
    unsigned short* __restrict__ w_ws, float* __restrict__ b_ws) {
  const int tid = threadIdx.x;
  const int wv = tid >> 6;
  const int l = tid & 63;
  const int q = l >> 4;

  // A frags (shared by all waves/tiles; L2-hot)
  bf16x8 Ah[16], Al[16];
#pragma unroll
  for (int s = 0; s < 16; ++s) {
    Ah[s] = *(const bf16x8*)&ah_ws[(size_t)(s * 64 + l) * 8];
    Al[s] = *(const bf16x8*)&al_ws[(size_t)(s * 64 + l) * 8];
  }

#pragma unroll 1
  for (int tt = 0; tt < 2; ++tt) {
    const int g = (blockIdx.x * 4 + wv) * 2 + tt;  // tile id 0..3359
    const int n0 = g * 16;
    const int n = n0 + (l & 15);

    // B stream: lane reads W[n][s*32 + q*8 .. +8]
    const float* bp = W + (size_t)n * 512 + q * 8;
    float4 ld[8][2];
#pragma unroll
    for (int s = 0; s < 8; ++s) {
      ld[s][0] = *(const float4*)(bp + s * 32);
      ld[s][1] = *(const float4*)(bp + s * 32 + 4);
    }

    f32x4 acc = {0.f, 0.f, 0.f, 0.f};
#pragma unroll
    for (int s = 0; s < 16; ++s) {
      const float4 b0 = ld[s & 7][0];
      const float4 b1 = ld[s & 7][1];
      if (s < 8) {
        ld[s][0] = *(const float4*)(bp + (s + 8) * 32);
        ld[s][1] = *(const float4*)(bp + (s + 8) * 32 + 4);
      }
      const float f[8] = {b0.x, b0.y, b0.z, b0.w, b1.x, b1.y, b1.z, b1.w};
      union { unsigned u[4]; bf16x8 v; } BH, BL;
#pragma unroll
      for (int p = 0; p < 4; ++p) {
        const unsigned u0 = __builtin_bit_cast(unsigned, f[2 * p]);
        const unsigned u1 = __builtin_bit_cast(unsigned, f[2 * p + 1]);
        const unsigned h0 = u0 & 0xFFFF0000u, h1 = u1 & 0xFFFF0000u;
        BH.u[p] = (h0 >> 16) | h1;
        const float lo0 = f[2 * p] - __builtin_bit_cast(float, h0);
        const float lo1 = f[2 * p + 1] - __builtin_bit_cast(float, h1);
        BL.u[p] = pk2(lo0, lo1);
      }
      acc = MFMA16(Ah[s], BH.v, acc);
      acc = MFMA16(Ah[s], BL.v, acc);
      acc = MFMA16(Al[s], BH.v, acc);
    }

    // epilogue: lane holds column n, samples b = q*4 + r
    const float bv = bias[n];
    if (n0 >= 53248) {  // conv biases: fp32, per-sample contiguous [512]
      const int j = n - 53248;
#pragma unroll
      for (int r = 0; r < 4; ++r) b_ws[(q * 4 + r) * 512 + j] = acc[r] + bv;
    } else {
      int fragbase, off, kbits;
      float scale;
      if (n < 8192)       { fragbase = 0;  off = 0;     kbits = 6; scale = 0.08838834764831845f; }
      else if (n < 24576) { fragbase = 16; off = 8192;  kbits = 7; scale = 0.08838834764831845f; }
      else if (n < 40960) { fragbase = 48; off = 24576; kbits = 7; scale = 0.08838834764831845f; }
      else if (n < 49152) { fragbase = 80; off = 40960; kbits = 7; scale = 0.125f; }
      else                { fragbase = 96; off = 49152; kbits = 6; scale = 0.125f; }
      const int r0 = n - off;
      const int m = r0 >> kbits;
      const int k = r0 & ((1 << kbits) - 1);
      const int mt = m >> 5, ks = k >> 4;
      const int lane = (m & 31) + 32 * ((k >> 3) & 1);
      const int j = k & 7;
      const int frag = fragbase + mt * (1 << (kbits - 4)) + ks;
      const size_t eoff = (size_t)frag * 512 + lane * 8 + j;  // in shorts
#pragma unroll
      for (int r = 0; r < 4; ++r) {
        const float v = (acc[r] + bv) * scale;
        w_ws[(size_t)(q * 4 + r) * WS_WSHORTS + eoff] = (unsigned short)bf16rne(v);
      }
    }
  }
}

// ---------------------------------------------------------------------------
// Kernel 2: per-sample conv chain. 512 blocks (sample = blk>>5, chunk=blk&31),
// 4 waves x 64 px/iter (two 32-px halves through the whole chain), 2 iters.
// LDS 66 KB -> 2 blocks/CU (2 waves/SIMD). mida A in LDS; in/midb/out/short A
// read per-use from global (L2-hot). No barriers in main loop.
// ---------------------------------------------------------------------------

DEVFN f32x16 bias_init(const float* bl, int mt, int lh) {
  f32x16 a;
#pragma unroll
  for (int g = 0; g < 4; ++g) {
    const float4 bv = *(const float4*)&bl[mt * 32 + 8 * g + 4 * lh];
    a[4 * g + 0] = bv.x; a[4 * g + 1] = bv.y;
    a[4 * g + 2] = bv.z; a[4 * g + 3] = bv.w;
  }
  return a;
}

// relu(acc) -> bf16 into wave-private 32-px h buffer (8 B-frags), in-place ok
DEVFN void write_h_half(short* H, int mt, int l31, int lh, const f32x16& a) {
#pragma unroll
  for (int g = 0; g < 4; ++g) {
    const int kstep = mt * 2 + (g >> 1);
    const int base = kstep * 512 + (l31 + 32 * (g & 1)) * 8 + lh * 4;
    uint2 w;
    w.x = pk2(fmaxf(a[4 * g + 0], 0.f), fmaxf(a[4 * g + 1], 0.f));
    w.y = pk2(fmaxf(a[4 * g + 2], 0.f), fmaxf(a[4 * g + 3], 0.f));
    *(uint2*)&H[base] = w;
  }
}

#define MFMA32(A, B, C) __builtin_amdgcn_mfma_f32_32x32x16_bf16((A), (B), (C), 0, 0, 0)

__global__ __launch_bounds__(256, 2) void dyn_conv(
    const float* __restrict__ x, const unsigned short* __restrict__ w_ws,
    const float* __restrict__ b_ws, float* __restrict__ out) {
  __shared__ short wl[32 * 512];   // mida A-frags: 32 KB
  __shared__ float bl[512];        //  2 KB
  __shared__ short hl[4][4096];    // per-wave h (8 B-frags): 32 KB

  const int s = blockIdx.x >> 5;
  const int chunk = blockIdx.x & 31;
  const int tid = threadIdx.x;
  const int wv = tid >> 6;
  const int l = tid & 63;
  const int l31 = l & 31;
  const int lh = l >> 5;

  const unsigned short* wbase = w_ws + (size_t)s * WS_WSHORTS;

  for (int f = wv; f < 32; f += 4)
    *(int4*)&wl[f * 512 + l * 8] = *(const int4*)&wbase[(16 + f) * 512 + l * 8];
  bl[tid] = b_ws[s * 512 + tid];
  bl[tid + 256] = b_ws[s * 512 + tid + 256];
  __syncthreads();

  short* H = &hl[wv][0];
  const float* xbase = x + (size_t)(s * 64) * 16384;
  float* obase = out + (size_t)(s * 64) * 16384;

  auto load_half = [&](int px, float xr[4][8]) {
#pragma unroll
    for (int ks = 0; ks < 4; ++ks) {
      const float* xp = xbase + (size_t)(ks * 16 + lh * 8) * 16384 + px + l31;
#pragma unroll
      for (int j = 0; j < 8; ++j) xr[ks][j] = xp[(size_t)j * 16384];
    }
  };
  auto pack_half = [&](const float xr[4][8], bf16x8 xf[4]) {
#pragma unroll
    for (int ks = 0; ks < 4; ++ks) {
      union { unsigned u[4]; bf16x8 v8; } uu;
#pragma unroll
      for (int j = 0; j < 4; ++j) uu.u[j] = pk2(xr[ks][2 * j], xr[ks][2 * j + 1]);
      xf[ks] = uu.v8;
    }
  };

  auto process_half = [&](int px, const bf16x8 xf[4]) {
    // ---- IN: h1 = relu(k_in @ x + b_in)     (M=128, K=64), A from global
#pragma unroll
    for (int mt = 0; mt < 4; ++mt) {
      f32x16 a = bias_init(bl + 0, mt, lh);
      bf16x8 A[4];
#pragma unroll
      for (int ks = 0; ks < 4; ++ks)
        A[ks] = *(const bf16x8*)&wbase[(size_t)(mt * 4 + ks) * 512 + l * 8];
#pragma unroll
      for (int ks = 0; ks < 4; ++ks) a = MFMA32(A[ks], xf[ks], a);
      write_h_half(H, mt, l31, lh, a);
    }

    bf16x8 hB[8];

    // ---- MIDA (A from LDS)                  (M=128, K=128)
#pragma unroll
    for (int i = 0; i < 8; ++i) hB[i] = *(const bf16x8*)&H[i * 512 + l * 8];
#pragma unroll
    for (int mt = 0; mt < 4; ++mt) {
      f32x16 a = bias_init(bl + 128, mt, lh);
#pragma unroll
      for (int ks = 0; ks < 8; ++ks) {
        const bf16x8 A = *(const bf16x8*)&wl[(mt * 8 + ks) * 512 + l * 8];
        a = MFMA32(A, hB[ks], a);
      }
      write_h_half(H, mt, l31, lh, a);
    }

    // ---- MIDB (A from global)               (M=128, K=128)
#pragma unroll
    for (int i = 0; i < 8; ++i) hB[i] = *(const bf16x8*)&H[i * 512 + l * 8];
#pragma unroll
    for (int mt = 0; mt < 4; ++mt) {
      f32x16 a = bias_init(bl + 256, mt, lh);
      bf16x8 A[8];
#pragma unroll
      for (int ks = 0; ks < 8; ++ks)
        A[ks] = *(const bf16x8*)&wbase[(size_t)(48 + mt * 8 + ks) * 512 + l * 8];
#pragma unroll
      for (int ks = 0; ks < 8; ++ks) a = MFMA32(A[ks], hB[ks], a);
      write_h_half(H, mt, l31, lh, a);
    }

    // ---- OUT: k_out@h3 + k_short@x + b_out + b_short   (M=64)
#pragma unroll
    for (int i = 0; i < 8; ++i) hB[i] = *(const bf16x8*)&H[i * 512 + l * 8];
#pragma unroll
    for (int mt = 0; mt < 2; ++mt) {
      f32x16 a = bias_init(bl + 384, mt, lh);
      {
        const f32x16 bs = bias_init(bl + 448, mt, lh);
#pragma unroll
        for (int e = 0; e < 16; ++e) a[e] += bs[e];
      }
      bf16x8 As[4], Ao[8];
#pragma unroll
      for (int ks = 0; ks < 4; ++ks)
        As[ks] = *(const bf16x8*)&wbase[(size_t)(96 + mt * 4 + ks) * 512 + l * 8];
#pragma unroll
      for (int ks = 0; ks < 8; ++ks)
        Ao[ks] = *(const bf16x8*)&wbase[(size_t)(80 + mt * 8 + ks) * 512 + l * 8];
#pragma unroll
      for (int ks = 0; ks < 4; ++ks) a = MFMA32(As[ks], xf[ks], a);
#pragma unroll
      for (int ks = 0; ks < 8; ++ks) a = MFMA32(Ao[ks], hB[ks], a);
#pragma unroll
      for (int g = 0; g < 4; ++g) {
#pragma unroll
        for (int qq = 0; qq < 4; ++qq) {
          const int row = mt * 32 + 8 * g + 4 * lh + qq;
          obase[(size_t)row * 16384 + px + l31] = a[4 * g + qq];
        }
      }
    }
  };

#pragma unroll 1
  for (int it = 0; it < 2; ++it) {
    const int px0 = chunk * 512 + it * 256 + wv * 64;
    float xr0[4][8], xr1[4][8];
    load_half(px0, xr0);
    load_half(px0 + 32, xr1);        // in flight through half-0 processing
    bf16x8 xf0[4], xf1[4];
    pack_half(xr0, xf0);
    process_half(px0, xf0);
    pack_half(xr1, xf1);
    process_half(px0 + 32, xf1);
  }
}

// ---------------------------------------------------------------------------
extern "C" void kernel_launch(void* const* d_in, const int* in_sizes, int n_in,
                              void* d_out, int out_size, void* d_ws,
                              size_t ws_size, hipStream_t stream) {
  (void)in_sizes; (void)n_in; (void)out_size; (void)ws_size;
  const float* x   = (const float*)d_in[0];
  const float* lat = (const float*)d_in[1];
  const float* W   = (const float*)d_in[2];
  const float* b   = (const float*)d_in[3];
  unsigned short* w_ws = (unsigned short*)d_ws;
  float* b_ws = (float*)((char*)d_ws + WS_BOFF);
  unsigned short* ah_ws = (unsigned short*)((char*)d_ws + WS_AHOFF);
  unsigned short* al_ws = (unsigned short*)((char*)d_ws + WS_ALOFF);
  float* out = (float*)d_out;

  lat_prep<<<dim3(4), dim3(256), 0, stream>>>(lat, ah_ws, al_ws);
  hyper_gemm<<<dim3(420), dim3(256), 0, stream>>>(W, b, ah_ws, al_ws, w_ws, b_ws);
  dyn_conv<<<dim3(512), dim3(256), 0, stream>>>(x, w_ws, b_ws, out);
}